// Round 1
// baseline (123.426 us; speedup 1.0000x reference)
//
#include <hip/hip_runtime.h>
#include <hip/hip_bf16.h>

// dist[b,c] = ||x_b||^2 + ||p_c||^2 - 2 x_b . p_c
// B=16384, D=512, C=1000 (padded to 1024 in workspace)

#define B_ROWS 16384
#define D_K    512
#define C_COLS 1000
#define C_PAD  1024

#define BM 128
#define BN 128
#define BK 32

typedef __attribute__((ext_vector_type(8))) short short8;
typedef __attribute__((ext_vector_type(4))) float f32x4;

// fp32 -> bf16 round-to-nearest-even
__device__ __forceinline__ unsigned short f2bf(float f) {
  unsigned u = __float_as_uint(f);
  u += 0x7fffu + ((u >> 16) & 1u);
  return (unsigned short)(u >> 16);
}

// 16-byte async global->LDS copy (lane-contiguous LDS destination)
__device__ __forceinline__ void gload16(const void* g, void* l) {
  __builtin_amdgcn_global_load_lds(
      (const __attribute__((address_space(1))) unsigned int*)g,
      (__attribute__((address_space(3))) unsigned int*)l, 16, 0, 0);
}

// One wave per row: cast row to bf16 + fp32 sum of squares.
// Rows [0, B_ROWS) -> x;  rows [B_ROWS, B_ROWS + C_PAD) -> protomat (zero-padded past C_COLS).
__global__ __launch_bounds__(256) void prep_kernel(
    const float* __restrict__ x, const float* __restrict__ p,
    unsigned short* __restrict__ xb, unsigned short* __restrict__ pb,
    float* __restrict__ xsq, float* __restrict__ psq) {
  const int wave = threadIdx.x >> 6;
  const int lane = threadIdx.x & 63;
  const int row  = blockIdx.x * 4 + wave;
  const bool isx = row < B_ROWS;
  const int r2   = isx ? row : row - B_ROWS;

  float v[8];
  if (isx) {
    const float4* s = reinterpret_cast<const float4*>(x + (size_t)r2 * D_K + lane * 8);
    float4 a = s[0], b = s[1];
    v[0] = a.x; v[1] = a.y; v[2] = a.z; v[3] = a.w;
    v[4] = b.x; v[5] = b.y; v[6] = b.z; v[7] = b.w;
  } else if (r2 < C_COLS) {
    const float4* s = reinterpret_cast<const float4*>(p + (size_t)r2 * D_K + lane * 8);
    float4 a = s[0], b = s[1];
    v[0] = a.x; v[1] = a.y; v[2] = a.z; v[3] = a.w;
    v[4] = b.x; v[5] = b.y; v[6] = b.z; v[7] = b.w;
  } else {
#pragma unroll
    for (int j = 0; j < 8; ++j) v[j] = 0.0f;
  }

  float ss = 0.0f;
  unsigned short u[8];
#pragma unroll
  for (int j = 0; j < 8; ++j) { ss += v[j] * v[j]; u[j] = f2bf(v[j]); }

  uint4 pk;
  pk.x = (unsigned)u[0] | ((unsigned)u[1] << 16);
  pk.y = (unsigned)u[2] | ((unsigned)u[3] << 16);
  pk.z = (unsigned)u[4] | ((unsigned)u[5] << 16);
  pk.w = (unsigned)u[6] | ((unsigned)u[7] << 16);
  unsigned short* dst = (isx ? xb : pb) + (size_t)r2 * D_K + lane * 8;
  *reinterpret_cast<uint4*>(dst) = pk;

#pragma unroll
  for (int off = 32; off > 0; off >>= 1) ss += __shfl_down(ss, off);
  if (lane == 0) (isx ? xsq : psq)[r2] = ss;
}

// m97-structure GEMM: 128x128 tile, BK=32, 4 waves (2x2), global_load_lds staging,
// 16x16x32 bf16 MFMA, fused distance epilogue.
__global__ __launch_bounds__(256, 2) void gemm_kernel(
    const unsigned short* __restrict__ xb, const unsigned short* __restrict__ pb,
    const float* __restrict__ xsq, const float* __restrict__ psq,
    float* __restrict__ out) {
  __shared__ __align__(16) unsigned short As[BM * BK];  // 8 KiB
  __shared__ __align__(16) unsigned short Bs[BN * BK];  // 8 KiB

  const int tid  = threadIdx.x;
  const int lane = tid & 63;
  const int wave = tid >> 6;
  const int wr   = wave >> 1;
  const int wc   = wave & 1;
  const int bm   = blockIdx.y;
  const int bn   = blockIdx.x;

  // Staging: chunk ch (0..511) = 16B = row ch>>2, k-offset (ch&3)*8 within the tile.
  const int ch0 = tid;
  const int ch1 = tid + 256;
  const unsigned short* a0 = xb + ((size_t)bm * BM + (ch0 >> 2)) * D_K + (ch0 & 3) * 8;
  const unsigned short* a1 = xb + ((size_t)bm * BM + (ch1 >> 2)) * D_K + (ch1 & 3) * 8;
  const unsigned short* b0 = pb + ((size_t)bn * BN + (ch0 >> 2)) * D_K + (ch0 & 3) * 8;
  const unsigned short* b1 = pb + ((size_t)bn * BN + (ch1 >> 2)) * D_K + (ch1 & 3) * 8;
  unsigned short* la0 = &As[ch0 * 8];
  unsigned short* la1 = &As[ch1 * 8];
  unsigned short* lb0 = &Bs[ch0 * 8];
  unsigned short* lb1 = &Bs[ch1 * 8];

  f32x4 acc[4][4];
#pragma unroll
  for (int i = 0; i < 4; ++i)
#pragma unroll
    for (int j = 0; j < 4; ++j) acc[i][j] = (f32x4){0.f, 0.f, 0.f, 0.f};

  const int mrow = wr * 64 + (lane & 15);
  const int ncol = wc * 64 + (lane & 15);
  const int koff = (lane >> 4) * 8;

#pragma unroll 1
  for (int ks = 0; ks < D_K / BK; ++ks) {
    const int ko = ks * BK;
    gload16(a0 + ko, la0);
    gload16(a1 + ko, la1);
    gload16(b0 + ko, lb0);
    gload16(b1 + ko, lb1);
    __syncthreads();  // drains vmcnt: LDS tiles ready

    short8 af[4], bf[4];
#pragma unroll
    for (int i = 0; i < 4; ++i)
      af[i] = *reinterpret_cast<const short8*>(&As[(mrow + i * 16) * BK + koff]);
#pragma unroll
    for (int j = 0; j < 4; ++j)
      bf[j] = *reinterpret_cast<const short8*>(&Bs[(ncol + j * 16) * BK + koff]);

#pragma unroll
    for (int i = 0; i < 4; ++i)
#pragma unroll
      for (int j = 0; j < 4; ++j)
        acc[i][j] = __builtin_amdgcn_mfma_f32_16x16x32_bf16(af[i], bf[j], acc[i][j], 0, 0, 0);

    __syncthreads();  // reads done before next stage overwrites
  }

  // Epilogue: out[b][c] = xsq[b] + psq[c] - 2*cross
  const int colbase = bn * BN + wc * 64 + (lane & 15);
  float pc[4];
#pragma unroll
  for (int j = 0; j < 4; ++j) pc[j] = psq[colbase + j * 16];  // C_PAD-sized: always in bounds

  const int rowbase = bm * BM + wr * 64 + ((lane >> 4) << 2);
#pragma unroll
  for (int i = 0; i < 4; ++i) {
#pragma unroll
    for (int r = 0; r < 4; ++r) {
      const int row = rowbase + i * 16 + r;
      const float xs = xsq[row];
#pragma unroll
      for (int j = 0; j < 4; ++j) {
        const int c = colbase + j * 16;
        if (c < C_COLS)
          out[(size_t)row * C_COLS + c] = xs + pc[j] - 2.0f * acc[i][j][r];
      }
    }
  }
}

extern "C" void kernel_launch(void* const* d_in, const int* in_sizes, int n_in,
                              void* d_out, int out_size, void* d_ws, size_t ws_size,
                              hipStream_t stream) {
  const float* x = (const float*)d_in[0];
  const float* p = (const float*)d_in[1];
  float* out = (float*)d_out;

  char* ws = (char*)d_ws;
  unsigned short* xb  = (unsigned short*)ws;                        // 16384*512*2 = 16 MiB
  unsigned short* pb  = (unsigned short*)(ws + 16777216);           // 1024*512*2  = 1 MiB
  float* xsq          = (float*)(ws + 16777216 + 1048576);          // 64 KiB
  float* psq          = (float*)(ws + 16777216 + 1048576 + 65536);  // 4 KiB

  // Prep: one wave per row, (16384 + 1024) rows / 4 waves per block
  prep_kernel<<<(B_ROWS + C_PAD) / 4, 256, 0, stream>>>(x, p, xb, pb, xsq, psq);

  // GEMM: N-tiles x M-tiles
  dim3 grid(C_PAD / BN, B_ROWS / BM, 1);
  gemm_kernel<<<grid, 256, 0, stream>>>(xb, pb, xsq, psq, out);
}

// Round 2
// 115.104 us; speedup vs baseline: 1.0723x; 1.0723x over previous
//
#include <hip/hip_runtime.h>
#include <hip/hip_bf16.h>

// dist[b,c] = ||x_b||^2 + ||p_c||^2 - 2 x_b . p_c
// B=16384, D=512, C=1000 (padded to 1024 in workspace)

#define B_ROWS 16384
#define D_K    512
#define C_COLS 1000
#define C_PAD  1024

#define BM 128
#define BN 128
#define BK 32
#define NK (D_K / BK)  // 16

typedef __attribute__((ext_vector_type(8))) short short8;
typedef __attribute__((ext_vector_type(4))) float f32x4;

// fp32 -> bf16 round-to-nearest-even
__device__ __forceinline__ unsigned short f2bf(float f) {
  unsigned u = __float_as_uint(f);
  u += 0x7fffu + ((u >> 16) & 1u);
  return (unsigned short)(u >> 16);
}

// 16-byte async global->LDS copy (lane-contiguous LDS destination)
__device__ __forceinline__ void gload16(const void* g, void* l) {
  __builtin_amdgcn_global_load_lds(
      (const __attribute__((address_space(1))) unsigned int*)g,
      (__attribute__((address_space(3))) unsigned int*)l, 16, 0, 0);
}

// One wave per row: cast row to bf16 + fp32 sum of squares.
// Rows [0, B_ROWS) -> x;  rows [B_ROWS, B_ROWS + C_PAD) -> protomat (zero-padded past C_COLS).
__global__ __launch_bounds__(256) void prep_kernel(
    const float* __restrict__ x, const float* __restrict__ p,
    unsigned short* __restrict__ xb, unsigned short* __restrict__ pb,
    float* __restrict__ xsq, float* __restrict__ psq) {
  const int wave = threadIdx.x >> 6;
  const int lane = threadIdx.x & 63;
  const int row  = blockIdx.x * 4 + wave;
  const bool isx = row < B_ROWS;
  const int r2   = isx ? row : row - B_ROWS;

  float v[8];
  if (isx) {
    const float4* s = reinterpret_cast<const float4*>(x + (size_t)r2 * D_K + lane * 8);
    float4 a = s[0], b = s[1];
    v[0] = a.x; v[1] = a.y; v[2] = a.z; v[3] = a.w;
    v[4] = b.x; v[5] = b.y; v[6] = b.z; v[7] = b.w;
  } else if (r2 < C_COLS) {
    const float4* s = reinterpret_cast<const float4*>(p + (size_t)r2 * D_K + lane * 8);
    float4 a = s[0], b = s[1];
    v[0] = a.x; v[1] = a.y; v[2] = a.z; v[3] = a.w;
    v[4] = b.x; v[5] = b.y; v[6] = b.z; v[7] = b.w;
  } else {
#pragma unroll
    for (int j = 0; j < 8; ++j) v[j] = 0.0f;
  }

  float ss = 0.0f;
  unsigned short u[8];
#pragma unroll
  for (int j = 0; j < 8; ++j) { ss += v[j] * v[j]; u[j] = f2bf(v[j]); }

  uint4 pk;
  pk.x = (unsigned)u[0] | ((unsigned)u[1] << 16);
  pk.y = (unsigned)u[2] | ((unsigned)u[3] << 16);
  pk.z = (unsigned)u[4] | ((unsigned)u[5] << 16);
  pk.w = (unsigned)u[6] | ((unsigned)u[7] << 16);
  unsigned short* dst = (isx ? xb : pb) + (size_t)r2 * D_K + lane * 8;
  *reinterpret_cast<uint4*>(dst) = pk;

#pragma unroll
  for (int off = 32; off > 0; off >>= 1) ss += __shfl_down(ss, off);
  if (lane == 0) (isx ? xsq : psq)[r2] = ss;
}

// 128x128 tile, BK=32, 4 waves (2x2), double-buffered LDS, chunk-permuted
// layout (bank-conflict-free ds_read_b128), XCD-aware block swizzle,
// 16x16x32 bf16 MFMA, fused distance epilogue.
//
// LDS layout: tile stored as 512 chunks of 16B. Fragment (row, kslot)
// [kslot = which 8-elem k-group of the 32-wide row] lives at chunk
//   idx(row, kslot) = row*4 + ((kslot + (row>>1)) & 3)
// Staging chunk ch therefore loads global k-group ((ch&3) - ((ch>>2)>>1)) & 3.
// Read position for wanted kslot: p = (kslot + ((row>>1)&3)) & 3.
__global__ __launch_bounds__(256, 4) void gemm_kernel(
    const unsigned short* __restrict__ xb, const unsigned short* __restrict__ pb,
    const float* __restrict__ xsq, const float* __restrict__ psq,
    float* __restrict__ out) {
  __shared__ __align__(16) unsigned short As[2][BM * BK];  // 2 x 8 KiB
  __shared__ __align__(16) unsigned short Bs[2][BN * BK];  // 2 x 8 KiB

  const int tid  = threadIdx.x;
  const int lane = tid & 63;
  const int wave = tid >> 6;
  const int wr   = wave >> 1;
  const int wc   = wave & 1;

  // XCD-aware swizzle: blocks bid with bid%8==x land on XCD x; give XCD x
  // tiles t in [x*128, (x+1)*128) = bm in [x*16, x*16+16), all bn.
  const int bid = blockIdx.x;
  const int tt  = (bid & 7) * 128 + (bid >> 3);
  const int bm  = tt >> 3;  // 0..127
  const int bn  = tt & 7;   // 0..7

  // Staging: chunk ch -> row = ch>>2, permuted global k-group.
  const int ch0 = tid;
  const int ch1 = tid + 256;
  const int r0  = ch0 >> 2, r1 = ch1 >> 2;
  const int kg0 = ((ch0 & 3) - (r0 >> 1)) & 3;
  const int kg1 = ((ch1 & 3) - (r1 >> 1)) & 3;
  const unsigned short* a0 = xb + ((size_t)bm * BM + r0) * D_K + kg0 * 8;
  const unsigned short* a1 = xb + ((size_t)bm * BM + r1) * D_K + kg1 * 8;
  const unsigned short* b0 = pb + ((size_t)bn * BN + r0) * D_K + kg0 * 8;
  const unsigned short* b1 = pb + ((size_t)bn * BN + r1) * D_K + kg1 * 8;

  f32x4 acc[4][4];
#pragma unroll
  for (int i = 0; i < 4; ++i)
#pragma unroll
    for (int j = 0; j < 4; ++j) acc[i][j] = (f32x4){0.f, 0.f, 0.f, 0.f};

  const int mrow = wr * 64 + (lane & 15);
  const int ncol = wc * 64 + (lane & 15);
  // Permuted read position for wanted kslot = lane>>4 (uniform across i).
  const int pslot = (((lane >> 4) + ((lane & 15) >> 1)) & 3);
  const int koffb = pslot * 8;

#define STAGE(T, BUF)                                   \
  do {                                                  \
    const int ko = (T)*BK;                              \
    gload16(a0 + ko, &As[BUF][ch0 * 8]);                \
    gload16(a1 + ko, &As[BUF][ch1 * 8]);                \
    gload16(b0 + ko, &Bs[BUF][ch0 * 8]);                \
    gload16(b1 + ko, &Bs[BUF][ch1 * 8]);                \
  } while (0)

#define COMPUTE(BUF)                                                          \
  do {                                                                        \
    short8 af[4], bfr[4];                                                     \
    _Pragma("unroll") for (int i = 0; i < 4; ++i)                             \
        af[i] = *reinterpret_cast<const short8*>(                             \
            &As[BUF][(mrow + i * 16) * BK + koffb]);                          \
    _Pragma("unroll") for (int j = 0; j < 4; ++j)                             \
        bfr[j] = *reinterpret_cast<const short8*>(                            \
            &Bs[BUF][(ncol + j * 16) * BK + koffb]);                          \
    _Pragma("unroll") for (int i = 0; i < 4; ++i)                             \
        _Pragma("unroll") for (int j = 0; j < 4; ++j)                         \
            acc[i][j] = __builtin_amdgcn_mfma_f32_16x16x32_bf16(              \
                af[i], bfr[j], acc[i][j], 0, 0, 0);                           \
  } while (0)

  STAGE(0, 0);
  __syncthreads();  // vmcnt(0): buf0 ready

#pragma unroll 1
  for (int t = 0; t < NK; t += 2) {
    STAGE(t + 1, 1);   // overlaps with compute of buf0
    COMPUTE(0);
    __syncthreads();   // drains stage(t+1) + all ds_reads of buf0
    if (t + 2 < NK) STAGE(t + 2, 0);
    COMPUTE(1);
    __syncthreads();
  }
#undef STAGE
#undef COMPUTE

  // Epilogue: out[b][c] = xsq[b] + psq[c] - 2*cross
  const int colbase = bn * BN + wc * 64 + (lane & 15);
  float pc[4];
#pragma unroll
  for (int j = 0; j < 4; ++j) pc[j] = psq[colbase + j * 16];  // C_PAD-sized: in bounds

  const int rowbase = bm * BM + wr * 64 + ((lane >> 4) << 2);
#pragma unroll
  for (int i = 0; i < 4; ++i) {
#pragma unroll
    for (int r = 0; r < 4; ++r) {
      const int row = rowbase + i * 16 + r;
      const float xs = xsq[row];
#pragma unroll
      for (int j = 0; j < 4; ++j) {
        const int c = colbase + j * 16;
        if (c < C_COLS)
          out[(size_t)row * C_COLS + c] = xs + pc[j] - 2.0f * acc[i][j][r];
      }
    }
  }
}

extern "C" void kernel_launch(void* const* d_in, const int* in_sizes, int n_in,
                              void* d_out, int out_size, void* d_ws, size_t ws_size,
                              hipStream_t stream) {
  const float* x = (const float*)d_in[0];
  const float* p = (const float*)d_in[1];
  float* out = (float*)d_out;

  char* ws = (char*)d_ws;
  unsigned short* xb  = (unsigned short*)ws;                        // 16384*512*2 = 16 MiB
  unsigned short* pb  = (unsigned short*)(ws + 16777216);           // 1024*512*2  = 1 MiB
  float* xsq          = (float*)(ws + 16777216 + 1048576);          // 64 KiB
  float* psq          = (float*)(ws + 16777216 + 1048576 + 65536);  // 4 KiB

  // Prep: one wave per row, (16384 + 1024) rows / 4 waves per block
  prep_kernel<<<(B_ROWS + C_PAD) / 4, 256, 0, stream>>>(x, p, xb, pb, xsq, psq);

  // GEMM: 1024 blocks, XCD-swizzled in-kernel
  gemm_kernel<<<1024, 256, 0, stream>>>(xb, pb, xsq, psq, out);
}